// Round 4
// baseline (160.899 us; speedup 1.0000x reference)
//
#include <hip/hip_runtime.h>
#include <hip/hip_fp16.h>

#define BLANKC 59

typedef _Float16 half8 __attribute__((ext_vector_type(8)));
typedef _Float16 half4 __attribute__((ext_vector_type(4)));

// Wave-wide shift-right-by-1 via DPP: VALU-speed cross-lane. Lane 0 gets `fill`.
__device__ __forceinline__ float wave_shr1(float x, float fill) {
    int r = __builtin_amdgcn_update_dpp(__float_as_int(fill), __float_as_int(x),
                                        0x138 /* WAVE_SHR:1 */, 0xF, 0xF, false);
    return __int_as_float(r);
}

template <int CTRL>
__device__ __forceinline__ float dpp_fmax(float x) {
    int r = __builtin_amdgcn_update_dpp(__float_as_int(x), __float_as_int(x),
                                        CTRL, 0xF, 0xF, false);
    return fmaxf(x, __int_as_float(r));
}

template <int CTRL>
__device__ __forceinline__ float dpp_addf(float x) {
    int r = __builtin_amdgcn_update_dpp(__float_as_int(x), __float_as_int(x),
                                        CTRL, 0xF, 0xF, false);
    return x + __int_as_float(r);
}

// Full-wave max, broadcast to all lanes (6 DPP fmax + readlane).
__device__ __forceinline__ float wave_max_bcast(float x) {
    x = dpp_fmax<0x111>(x);   // row_shr:1
    x = dpp_fmax<0x112>(x);   // row_shr:2
    x = dpp_fmax<0x114>(x);   // row_shr:4
    x = dpp_fmax<0x118>(x);   // row_shr:8
    x = dpp_fmax<0x142>(x);   // row_bcast:15
    x = dpp_fmax<0x143>(x);   // row_bcast:31
    return __int_as_float(__builtin_amdgcn_readlane(__float_as_int(x), 63));
}

// ---------------- Barrier-free producer/consumer fused CTC ------------------
// One block per batch element. Wave 0: scanner (linear-domain alpha).
// Waves 1-3: producers, wave w owns t-range [(w-1)*128, w*128), emitting
// 8-t passes into the full-T emission array S and releasing an LDS flag.
// The scanner acquire-polls flags and trails; producers NEVER wait, so HBM
// loads stream continuously for the whole kernel. No __syncthreads after
// the prologue.
#define RS   392   // S row stride in halves: 784 B = 49 16B-chunks (chunk 48 = XOR spill)
#define NCH  48    // T/8 chunks
#define SCRS 68    // producer scratch row stride in halves (136 B: bank-staggered)

__global__ __launch_bounds__(256)
void ctc_fused(const int* __restrict__ labels, const float* __restrict__ logits,
               float* __restrict__ out, int T, int V, int L, float inv_b) {
    const int b    = blockIdx.x;
    const int tid  = threadIdx.x;
    const int lane = tid & 63;
    const int wid  = tid >> 6;

    __shared__ __align__(16) __half S[46 * RS];      // 36.1 KB, write-once
    __shared__ __align__(16) __half scr[3][8][SCRS]; // 3.3 KB per-wave softmax bounce
    __shared__ int labs[64];
    __shared__ int flags[4];                         // passes completed per producer

    if (tid < 64) labs[tid] = (tid < L) ? labels[(long)b * L + tid] : BLANKC;
    if (tid < 4)  flags[tid] = 0;
    __syncthreads();                                 // the ONLY block-wide barrier

    if (wid != 0) {
        // ---------------- producer: 16 passes of 8 t each -------------------
        const int w  = wid - 1;                      // 0..2
        const int tq = lane >> 3;                    // t within pass (0..7)
        const int q  = lane & 7;                     // column group
        const int c0 = q * 8;                        // cols c0..c0+7 (q=7: 56..59)
        const bool full = (q < 7);
        const float* src = logits + (long)b * T * V;

        // per-lane gather assignments (pass-invariant): 46 slots x 8 t = 368
        int gl[6], gr[6], gv[6]; bool gok[6];
        #pragma unroll
        for (int k = 0; k < 6; ++k) {
            const int i = lane + (k << 6);
            gok[k] = (i < 368);
            gl[k] = i >> 3; gr[k] = i & 7;
            const int ll = gok[k] ? gl[k] : 0;
            gv[k] = (ll < 45) ? labs[ll] : BLANKC;
        }

        float4 A0, A1{0.f,0.f,0.f,0.f}, B0{0.f,0.f,0.f,0.f}, B1;
        {   const float* p = src + (w * 128 + tq) * 60 + c0;
            A0 = *(const float4*)p;
            if (full) A1 = *(const float4*)(p + 4);
        }
        for (int pass = 0; pass < 16; ++pass) {
            const int tbase = w * 128 + pass * 8;
            B1 = float4{0.f,0.f,0.f,0.f};
            if (pass < 15) {                         // prefetch next pass
                const float* p = src + (tbase + 8 + tq) * 60 + c0;
                B0 = *(const float4*)p;
                if (full) B1 = *(const float4*)(p + 4);
            }
            // register softmax over this t's 60 logits (8 lanes cooperate)
            const float e0 = __expf(A0.x), e1 = __expf(A0.y),
                        e2 = __expf(A0.z), e3 = __expf(A0.w);
            float e4 = 0.f, e5 = 0.f, e6 = 0.f, e7 = 0.f;
            if (full) { e4 = __expf(A1.x); e5 = __expf(A1.y);
                        e6 = __expf(A1.z); e7 = __expf(A1.w); }
            float s = ((e0 + e1) + (e2 + e3)) + ((e4 + e5) + (e6 + e7));
            s = dpp_addf<0xB1>(s);                   // quad_perm xor1
            s = dpp_addf<0x4E>(s);                   // quad_perm xor2
            s += __shfl_xor(s, 4, 64);               // xor4 -> sum over 8 lanes
            const float inv = __builtin_amdgcn_rcpf(s);
            const half4 p0 = { (_Float16)(e0 * inv), (_Float16)(e1 * inv),
                               (_Float16)(e2 * inv), (_Float16)(e3 * inv) };
            const half4 p1 = { (_Float16)(e4 * inv), (_Float16)(e5 * inv),
                               (_Float16)(e6 * inv), (_Float16)(e7 * inv) };
            *(half4*)&scr[w][tq][c0]     = p0;
            *(half4*)&scr[w][tq][c0 + 4] = p1;
            __threadfence_block();                   // wave-local: writes complete

            // gather 46 slots x 8 t into S (chunk-XOR swizzled for banks)
            const int c = tbase >> 3;                // uniform chunk index
            #pragma unroll
            for (int k = 0; k < 6; ++k) {
                if (gok[k]) {
                    const int cp = c ^ ((gl[k] >> 3) & 7);
                    S[gl[k] * RS + cp * 8 + gr[k]] = scr[w][gr[k]][gv[k]];
                }
            }
            __threadfence_block();                   // S writes visible
            if (lane == 0)
                __hip_atomic_fetch_add(&flags[w], 1, __ATOMIC_RELEASE,
                                       __HIP_MEMORY_SCOPE_WORKGROUP);
            A0 = B0; A1 = B1;
        }
        return;
    }

    // ---------------- scanner: wave 0 ---------------------------------------
    const int labL = (lane < L) ? labs[lane] : BLANKC;
    const int labP = (lane >= 1 && lane < L) ? labs[lane - 1] : BLANKC;
    const float skipf = ((lane >= 1) && (lane < L) && (labL != BLANKC) && (labL != labP))
                        ? 1.0f : 0.0f;
    const unsigned long long mk = __ballot((lane < L) && (labL != BLANKC));
    const int len = __popcll(mk);

    const int rl = (lane < 45) ? lane : 45;          // lanes>=45: masked to 0 below
    const __half* baseL = &S[rl * RS];
    const __half* baseB = &S[45 * RS];
    const int xL = (rl >> 3) & 7;                    // chunk-XOR keys
    const int xB = 5;                                // (45>>3)&7

    float a0 = 0.f, a1 = 0.f;
    int esum = 0;

    auto step = [&](float eL, float eB) {
        const float p   = wave_shr1(a1, 0.0f);       // alpha_old[2l-1]
        const float t1  = a0 + a1;
        const float na0 = (a0 + p) * eB;
        const float na1 = fmaf(skipf, p, t1) * eL;
        a0 = na0; a1 = na1;
    };
    auto renorm = [&]() {
        const float m = wave_max_bcast(fmaxf(a0, a1));
        const int e = (__float_as_int(m) >> 23) & 0xff;
        int sexp = 207 - e;                          // scale max to ~2^80
        if (sexp > 127) sexp = 127;
        const float sc = __int_as_float((sexp + 127) << 23);
        a0 *= sc; a1 *= sc;
        esum += sexp;
    };

    int seen = 0, curw = -1;
    auto waitc = [&](int c) {                        // consume chunks in order
        const int w = c >> 4, pw = c & 15;
        if (w != curw) {
            curw = w;
            seen = __hip_atomic_load(&flags[w], __ATOMIC_ACQUIRE,
                                     __HIP_MEMORY_SCOPE_WORKGROUP);
        }
        while (seen <= pw) {
            __builtin_amdgcn_s_sleep(2);
            seen = __hip_atomic_load(&flags[curw], __ATOMIC_ACQUIRE,
                                     __HIP_MEMORY_SCOPE_WORKGROUP);
        }
    };
    const half8 hz = {};
    auto loadch = [&](int c, half8& hL, half8& hB) {
        hL = *(const half8*)(baseL + (c ^ xL) * 8);
        hB = *(const half8*)(baseB + (c ^ xB) * 8);
        if (lane >= 45) hL = hz;                     // phantom s1 rows
        if (lane >= 46) hB = hz;                     // phantom s0 rows
    };

    half8 cL, cB, nL, nB;
    waitc(0);
    loadch(0, cL, cB);
    for (int c = 0; c < NCH; ++c) {
        if (c + 1 < NCH) { waitc(c + 1); loadch(c + 1, nL, nB); }  // prefetch
        if (c == 0) {
            a0 = (lane == 0) ? (float)cB[0] * 0x1p80f : 0.f;
            a1 = (lane == 0) ? (float)cL[0] * 0x1p80f : 0.f;
            esum = 80;
            #pragma unroll
            for (int i = 1; i < 8; ++i) step((float)cL[i], (float)cB[i]);
        } else {
            #pragma unroll
            for (int i = 0; i < 8; ++i) step((float)cL[i], (float)cB[i]);
        }
        renorm();
        cL = nL; cB = nB;
    }

    // epilogue: end = 2*len -> lane len's a0; end-1 -> lane (len-1)'s a1
    const float ab2 = __shfl(a0, len, 64);
    float al2 = __shfl(a1, (len > 0) ? len - 1 : 0, 64);
    al2 = (len > 0) ? al2 : 0.f;
    if (lane == 0) {
        const float s   = ab2 + al2;
        const float nll = -(__logf(s) - (float)esum * 0.69314718056f);
        atomicAdd(out, nll * inv_b);
    }
}

extern "C" void kernel_launch(void* const* d_in, const int* in_sizes, int n_in,
                              void* d_out, int out_size, void* d_ws, size_t ws_size,
                              hipStream_t stream) {
    const int* labels   = (const int*)d_in[0];
    const float* logits = (const float*)d_in[1];
    float* out          = (float*)d_out;
    (void)d_ws; (void)ws_size;

    const int L = 45, V = 60;
    const int B = in_sizes[0] / L;
    const int T = in_sizes[1] / (B * V);

    hipMemsetAsync(out, 0, (size_t)out_size * sizeof(float), stream);
    ctc_fused<<<B, 256, 0, stream>>>(labels, logits, out, T, V, L, 1.0f / (float)B);
}

// Round 5
// 159.700 us; speedup vs baseline: 1.0075x; 1.0075x over previous
//
#include <hip/hip_runtime.h>
#include <hip/hip_fp16.h>

#define BLANKC 59

typedef _Float16 half8 __attribute__((ext_vector_type(8)));
typedef _Float16 half4 __attribute__((ext_vector_type(4)));

// LDS-only fence: waits LDS/SMEM queue, leaves global prefetches (vmcnt) in
// flight. __threadfence_block would drain vmcnt(0) and kill the pipeline.
#define LDS_FENCE() asm volatile("s_waitcnt lgkmcnt(0)" ::: "memory")

// Wave-wide shift-right-by-1 via DPP: VALU-speed cross-lane. Lane 0 gets `fill`.
__device__ __forceinline__ float wave_shr1(float x, float fill) {
    int r = __builtin_amdgcn_update_dpp(__float_as_int(fill), __float_as_int(x),
                                        0x138 /* WAVE_SHR:1 */, 0xF, 0xF, false);
    return __int_as_float(r);
}

template <int CTRL>
__device__ __forceinline__ float dpp_fmax(float x) {
    int r = __builtin_amdgcn_update_dpp(__float_as_int(x), __float_as_int(x),
                                        CTRL, 0xF, 0xF, false);
    return fmaxf(x, __int_as_float(r));
}

template <int CTRL>
__device__ __forceinline__ float dpp_addf(float x) {
    int r = __builtin_amdgcn_update_dpp(__float_as_int(x), __float_as_int(x),
                                        CTRL, 0xF, 0xF, false);
    return x + __int_as_float(r);
}

// Full-wave max, broadcast to all lanes (6 DPP fmax + readlane).
__device__ __forceinline__ float wave_max_bcast(float x) {
    x = dpp_fmax<0x111>(x);   // row_shr:1
    x = dpp_fmax<0x112>(x);   // row_shr:2
    x = dpp_fmax<0x114>(x);   // row_shr:4
    x = dpp_fmax<0x118>(x);   // row_shr:8
    x = dpp_fmax<0x142>(x);   // row_bcast:15
    x = dpp_fmax<0x143>(x);   // row_bcast:31
    return __int_as_float(__builtin_amdgcn_readlane(__float_as_int(x), 63));
}

// ---------------- Barrier-free producer/consumer fused CTC ------------------
// One block per batch element. Wave 0: scanner (linear-domain alpha).
// Waves 1-3: producers, wave w owns t-range [(w-1)*128, w*128), emitting
// 8-t passes into the full-T emission array S and releasing an LDS flag.
// Producers never wait on anything and their global prefetches stay in
// flight across passes (LDS-only fences); the scanner acquire-polls flags.
#define RS   392   // S row stride in halves: 784 B = 49 16B-chunks (chunk 48 = XOR spill)
#define NCH  48    // T/8 chunks
#define SCRS 68    // producer scratch row stride in halves (136 B: bank-staggered)

__global__ __launch_bounds__(256)
void ctc_fused(const int* __restrict__ labels, const float* __restrict__ logits,
               float* __restrict__ out, int T, int V, int L, float inv_b) {
    const int b    = blockIdx.x;
    const int tid  = threadIdx.x;
    const int lane = tid & 63;
    const int wid  = tid >> 6;

    __shared__ __align__(16) __half S[46 * RS];      // 36.1 KB, write-once
    __shared__ __align__(16) __half scr[3][8][SCRS]; // 3.3 KB per-wave softmax bounce
    __shared__ int labs[64];
    __shared__ int flags[4];                         // passes completed per producer

    if (tid < 64) labs[tid] = (tid < L) ? labels[(long)b * L + tid] : BLANKC;
    if (tid < 4)  flags[tid] = 0;
    __syncthreads();                                 // the ONLY block-wide barrier

    if (wid != 0) {
        // ---------------- producer: 16 passes of 8 t each -------------------
        const int w  = wid - 1;                      // 0..2
        const int tq = lane >> 3;                    // t within pass (0..7)
        const int q  = lane & 7;                     // column group
        const int c0 = q * 8;                        // cols c0..c0+7 (q=7: 56..59)
        const bool full = (q < 7);
        const float* src = logits + (long)b * T * V;

        // per-lane gather assignments (pass-invariant): 46 slots x 8 t = 368
        int gl[6], gr[6], gv[6]; bool gok[6];
        #pragma unroll
        for (int k = 0; k < 6; ++k) {
            const int i = lane + (k << 6);
            gok[k] = (i < 368);
            gl[k] = i >> 3; gr[k] = i & 7;
            const int ll = gok[k] ? gl[k] : 0;
            gv[k] = (ll < 45) ? labs[ll] : BLANKC;
        }

        float4 A0, A1{0.f,0.f,0.f,0.f}, B0{0.f,0.f,0.f,0.f}, B1;
        {   const float* p = src + (w * 128 + tq) * 60 + c0;
            A0 = *(const float4*)p;
            if (full) A1 = *(const float4*)(p + 4);
        }
        for (int pass = 0; pass < 16; ++pass) {
            const int tbase = w * 128 + pass * 8;
            B1 = float4{0.f,0.f,0.f,0.f};
            if (pass < 15) {                         // prefetch next pass
                const float* p = src + (tbase + 8 + tq) * 60 + c0;
                B0 = *(const float4*)p;
                if (full) B1 = *(const float4*)(p + 4);
            }
            // register softmax over this t's 60 logits (8 lanes cooperate)
            const float e0 = __expf(A0.x), e1 = __expf(A0.y),
                        e2 = __expf(A0.z), e3 = __expf(A0.w);
            float e4 = 0.f, e5 = 0.f, e6 = 0.f, e7 = 0.f;
            if (full) { e4 = __expf(A1.x); e5 = __expf(A1.y);
                        e6 = __expf(A1.z); e7 = __expf(A1.w); }
            float s = ((e0 + e1) + (e2 + e3)) + ((e4 + e5) + (e6 + e7));
            s = dpp_addf<0xB1>(s);                   // quad_perm xor1
            s = dpp_addf<0x4E>(s);                   // quad_perm xor2
            s += __shfl_xor(s, 4, 64);               // xor4 -> sum over 8 lanes
            const float inv = __builtin_amdgcn_rcpf(s);
            const half4 p0 = { (_Float16)(e0 * inv), (_Float16)(e1 * inv),
                               (_Float16)(e2 * inv), (_Float16)(e3 * inv) };
            const half4 p1 = { (_Float16)(e4 * inv), (_Float16)(e5 * inv),
                               (_Float16)(e6 * inv), (_Float16)(e7 * inv) };
            *(half4*)&scr[w][tq][c0]     = p0;
            *(half4*)&scr[w][tq][c0 + 4] = p1;
            LDS_FENCE();                             // scr writes retired (LDS only)

            // gather 46 slots x 8 t into S (chunk-XOR swizzled for banks)
            const int c = tbase >> 3;                // uniform chunk index
            #pragma unroll
            for (int k = 0; k < 6; ++k) {
                if (gok[k]) {
                    const int cp = c ^ ((gl[k] >> 3) & 7);
                    S[gl[k] * RS + cp * 8 + gr[k]] = scr[w][gr[k]][gv[k]];
                }
            }
            LDS_FENCE();                             // S writes retired before flag
            if (lane == 0)
                __hip_atomic_fetch_add(&flags[w], 1, __ATOMIC_RELAXED,
                                       __HIP_MEMORY_SCOPE_WORKGROUP);
            A0 = B0; A1 = B1;
        }
        return;
    }

    // ---------------- scanner: wave 0 ---------------------------------------
    const int labL = (lane < L) ? labs[lane] : BLANKC;
    const int labP = (lane >= 1 && lane < L) ? labs[lane - 1] : BLANKC;
    const float skipf = ((lane >= 1) && (lane < L) && (labL != BLANKC) && (labL != labP))
                        ? 1.0f : 0.0f;
    const unsigned long long mk = __ballot((lane < L) && (labL != BLANKC));
    const int len = __popcll(mk);

    const int rl = (lane < 45) ? lane : 45;          // lanes>=45: masked to 0 below
    const __half* baseL = &S[rl * RS];
    const __half* baseB = &S[45 * RS];
    const int xL = (rl >> 3) & 7;                    // chunk-XOR keys
    const int xB = 5;                                // (45>>3)&7

    float a0 = 0.f, a1 = 0.f;
    int esum = 0;

    auto step = [&](float eL, float eB) {
        const float p   = wave_shr1(a1, 0.0f);       // alpha_old[2l-1]
        const float t1  = a0 + a1;
        const float na0 = (a0 + p) * eB;
        const float na1 = fmaf(skipf, p, t1) * eL;
        a0 = na0; a1 = na1;
    };
    auto renorm = [&]() {
        const float m = wave_max_bcast(fmaxf(a0, a1));
        const int e = (__float_as_int(m) >> 23) & 0xff;
        int sexp = 207 - e;                          // scale max to ~2^80
        if (sexp > 127) sexp = 127;
        const float sc = __int_as_float((sexp + 127) << 23);
        a0 *= sc; a1 *= sc;
        esum += sexp;
    };

    int seen = 0, curw = -1;
    auto waitc = [&](int c) {                        // consume chunks in order
        const int w = c >> 4, pw = c & 15;
        if (w != curw) {
            curw = w;
            seen = __hip_atomic_load(&flags[w], __ATOMIC_RELAXED,
                                     __HIP_MEMORY_SCOPE_WORKGROUP);
        }
        while (seen <= pw) {
            __builtin_amdgcn_s_sleep(2);
            seen = __hip_atomic_load(&flags[curw], __ATOMIC_RELAXED,
                                     __HIP_MEMORY_SCOPE_WORKGROUP);
        }
        asm volatile("" ::: "memory");               // no hoisting S reads above poll
    };
    const half8 hz = {};
    auto loadch = [&](int c, half8& hL, half8& hB) {
        hL = *(const half8*)(baseL + (c ^ xL) * 8);
        hB = *(const half8*)(baseB + (c ^ xB) * 8);
        if (lane >= 45) hL = hz;                     // phantom s1 rows
        if (lane >= 46) hB = hz;                     // phantom s0 rows
    };

    half8 cL, cB, nL, nB;
    waitc(0);
    loadch(0, cL, cB);
    for (int c = 0; c < NCH; ++c) {
        if (c + 1 < NCH) { waitc(c + 1); loadch(c + 1, nL, nB); }  // prefetch
        if (c == 0) {
            a0 = (lane == 0) ? (float)cB[0] * 0x1p80f : 0.f;
            a1 = (lane == 0) ? (float)cL[0] * 0x1p80f : 0.f;
            esum = 80;
            #pragma unroll
            for (int i = 1; i < 8; ++i) step((float)cL[i], (float)cB[i]);
        } else {
            #pragma unroll
            for (int i = 0; i < 8; ++i) step((float)cL[i], (float)cB[i]);
        }
        renorm();
        cL = nL; cB = nB;
    }

    // epilogue: end = 2*len -> lane len's a0; end-1 -> lane (len-1)'s a1
    const float ab2 = __shfl(a0, len, 64);
    float al2 = __shfl(a1, (len > 0) ? len - 1 : 0, 64);
    al2 = (len > 0) ? al2 : 0.f;
    if (lane == 0) {
        const float s   = ab2 + al2;
        const float nll = -(__logf(s) - (float)esum * 0.69314718056f);
        atomicAdd(out, nll * inv_b);
    }
}

extern "C" void kernel_launch(void* const* d_in, const int* in_sizes, int n_in,
                              void* d_out, int out_size, void* d_ws, size_t ws_size,
                              hipStream_t stream) {
    const int* labels   = (const int*)d_in[0];
    const float* logits = (const float*)d_in[1];
    float* out          = (float*)d_out;
    (void)d_ws; (void)ws_size;

    const int L = 45, V = 60;
    const int B = in_sizes[0] / L;
    const int T = in_sizes[1] / (B * V);

    hipMemsetAsync(out, 0, (size_t)out_size * sizeof(float), stream);
    ctc_fused<<<B, 256, 0, stream>>>(labels, logits, out, T, V, L, 1.0f / (float)B);
}

// Round 7
// 154.771 us; speedup vs baseline: 1.0396x; 1.0319x over previous
//
#include <hip/hip_runtime.h>
#include <hip/hip_fp16.h>

#define BLANKC 59

typedef _Float16 half8 __attribute__((ext_vector_type(8)));
typedef _Float16 half4 __attribute__((ext_vector_type(4)));

// LDS-only fence: waits LDS queue, leaves global prefetches (vmcnt) in flight.
#define LDS_FENCE() asm volatile("s_waitcnt lgkmcnt(0)" ::: "memory")

// lane l <- lane l-1 (fill into lane 0)
__device__ __forceinline__ float wave_shr1(float x, float fill) {
    int r = __builtin_amdgcn_update_dpp(__float_as_int(fill), __float_as_int(x),
                                        0x138 /* WAVE_SHR:1 */, 0xF, 0xF, false);
    return __int_as_float(r);
}
// lane l <- lane l+1 (fill into lane 63)
__device__ __forceinline__ float wave_shl1(float x, float fill) {
    int r = __builtin_amdgcn_update_dpp(__float_as_int(fill), __float_as_int(x),
                                        0x130 /* WAVE_SHL:1 */, 0xF, 0xF, false);
    return __int_as_float(r);
}

template <int CTRL>
__device__ __forceinline__ float dpp_fmax(float x) {
    int r = __builtin_amdgcn_update_dpp(__float_as_int(x), __float_as_int(x),
                                        CTRL, 0xF, 0xF, false);
    return fmaxf(x, __int_as_float(r));
}
template <int CTRL>
__device__ __forceinline__ float dpp_addf(float x) {
    int r = __builtin_amdgcn_update_dpp(__float_as_int(x), __float_as_int(x),
                                        CTRL, 0xF, 0xF, false);
    return x + __int_as_float(r);
}
__device__ __forceinline__ float wave_max_bcast(float x) {
    x = dpp_fmax<0x111>(x); x = dpp_fmax<0x112>(x);
    x = dpp_fmax<0x114>(x); x = dpp_fmax<0x118>(x);
    x = dpp_fmax<0x142>(x); x = dpp_fmax<0x143>(x);
    return __int_as_float(__builtin_amdgcn_readlane(__float_as_int(x), 63));
}
__device__ __forceinline__ float wave_sum_bcast(float x) {
    x = dpp_addf<0x111>(x); x = dpp_addf<0x112>(x);
    x = dpp_addf<0x114>(x); x = dpp_addf<0x118>(x);
    x = dpp_addf<0x142>(x); x = dpp_addf<0x143>(x);
    return __int_as_float(__builtin_amdgcn_readlane(__float_as_int(x), 63));
}

// ---------------- Fwd/Bwd-split producer/consumer fused CTC -----------------
// One block per batch element. Wave 0: FORWARD alpha scan t=0..191.
// Wave 1: BACKWARD beta scan t=383..192 (concurrent: serial chain per element
// halves, 384 -> 192 steps). Waves 2,3: producers (wave 2: chunks 0..23
// ascending; wave 3: chunks 47..24 descending). Join at t=191/192 in LOG2
// domain: the two unconditioned profiles peak at opposite ends of the state
// axis, so linear-domain products flush to zero (fp32 denormal flush) -> the
// round-6 inf. log2 join is flush-proof.
#define RS   392   // S row stride in halves (49 16B-chunks; chunk-XOR swizzle room)
#define SCRS 68    // producer scratch row stride in halves

__global__ __launch_bounds__(256)
void ctc_fused(const int* __restrict__ labels, const float* __restrict__ logits,
               float* __restrict__ out, int T, int V, int L, float inv_b) {
    const int b    = blockIdx.x;
    const int tid  = threadIdx.x;
    const int lane = tid & 63;
    const int wid  = tid >> 6;

    __shared__ __align__(16) __half S[46 * RS];      // 36.1 KB, write-once
    __shared__ __align__(16) __half scr[2][8][SCRS]; // 2.2 KB softmax bounce
    __shared__ float fa0[64], fa1[64];               // fwd result for the join
    __shared__ int labs[64];
    __shared__ int flags[2];                         // passes done per producer
    __shared__ int esF_s, wdone;

    if (tid < 64) labs[tid] = (tid < L) ? labels[(long)b * L + tid] : BLANKC;
    if (tid == 0) { flags[0] = 0; flags[1] = 0; wdone = 0; }
    __syncthreads();                                 // the ONLY block-wide barrier

    if (wid >= 2) {
        // ---------------- producer: 24 passes of 8 t each -------------------
        const int h  = wid - 2;                      // 0: fwd half, 1: bwd half
        const int tq = lane >> 3;                    // t within pass (0..7)
        const int q  = lane & 7;                     // column group
        const int c0 = q * 8;
        const bool full = (q < 7);
        const float* src = logits + (long)b * T * V;

        int gl[6], gr[6], gv[6]; bool gok[6];
        #pragma unroll
        for (int k = 0; k < 6; ++k) {
            const int i = lane + (k << 6);
            gok[k] = (i < 368);                      // 46 slots x 8 t
            gl[k] = i >> 3; gr[k] = i & 7;
            const int ll = gok[k] ? gl[k] : 0;
            gv[k] = (ll < 45) ? labs[ll] : BLANKC;
        }

        float4 A0, A1{0.f,0.f,0.f,0.f}, B0{0.f,0.f,0.f,0.f}, B1;
        {   const int ch0 = h ? 47 : 0;
            const float* p = src + (ch0 * 8 + tq) * 60 + c0;
            A0 = *(const float4*)p;
            if (full) A1 = *(const float4*)(p + 4);
        }
        for (int pass = 0; pass < 24; ++pass) {
            const int ch = h ? (47 - pass) : pass;   // chunk produced this pass
            B1 = float4{0.f,0.f,0.f,0.f};
            if (pass < 23) {                         // prefetch next pass
                const int ch2 = h ? (46 - pass) : (pass + 1);
                const float* p = src + (ch2 * 8 + tq) * 60 + c0;
                B0 = *(const float4*)p;
                if (full) B1 = *(const float4*)(p + 4);
            }
            // register softmax over this t's 60 logits (8 lanes cooperate)
            const float e0 = __expf(A0.x), e1 = __expf(A0.y),
                        e2 = __expf(A0.z), e3 = __expf(A0.w);
            float e4 = 0.f, e5 = 0.f, e6 = 0.f, e7 = 0.f;
            if (full) { e4 = __expf(A1.x); e5 = __expf(A1.y);
                        e6 = __expf(A1.z); e7 = __expf(A1.w); }
            float s = ((e0 + e1) + (e2 + e3)) + ((e4 + e5) + (e6 + e7));
            s = dpp_addf<0xB1>(s);                   // quad_perm xor1
            s = dpp_addf<0x4E>(s);                   // quad_perm xor2
            s += __shfl_xor(s, 4, 64);
            const float inv = __builtin_amdgcn_rcpf(s);
            const half4 p0 = { (_Float16)(e0 * inv), (_Float16)(e1 * inv),
                               (_Float16)(e2 * inv), (_Float16)(e3 * inv) };
            const half4 p1 = { (_Float16)(e4 * inv), (_Float16)(e5 * inv),
                               (_Float16)(e6 * inv), (_Float16)(e7 * inv) };
            *(half4*)&scr[h][tq][c0]     = p0;
            *(half4*)&scr[h][tq][c0 + 4] = p1;
            LDS_FENCE();                             // scr retired (LDS only)

            #pragma unroll
            for (int k = 0; k < 6; ++k) {            // gather into S (swizzled)
                if (gok[k]) {
                    const int cp = ch ^ ((gl[k] >> 3) & 7);
                    S[gl[k] * RS + cp * 8 + gr[k]] = scr[h][gr[k]][gv[k]];
                }
            }
            LDS_FENCE();                             // S retired before flag
            if (lane == 0)
                __hip_atomic_fetch_add(&flags[h], 1, __ATOMIC_RELAXED,
                                       __HIP_MEMORY_SCOPE_WORKGROUP);
            A0 = B0; A1 = B1;
        }
        return;
    }

    // ---------------- scanners (waves 0,1) ----------------------------------
    const int labL = (lane < L) ? labs[lane] : BLANKC;
    const int labP = (lane >= 1 && lane < L) ? labs[lane - 1] : BLANKC;
    const float skipf = ((lane >= 1) && (lane < L) && (labL != BLANKC) && (labL != labP))
                        ? 1.0f : 0.0f;
    const unsigned long long mk = __ballot((lane < L) && (labL != BLANKC));
    const int len = __popcll(mk);

    const int rl = (lane < 45) ? lane : 45;
    const __half* baseL = &S[rl * RS];
    const __half* baseB = &S[45 * RS];
    const int xL = (rl >> 3) & 7;                    // chunk-XOR keys
    const int xB = 5;                                // (45>>3)&7

    const half8 hz = {};
    auto loadch = [&](int c, half8& hL, half8& hB) {
        hL = *(const half8*)(baseL + (c ^ xL) * 8);
        hB = *(const half8*)(baseB + (c ^ xB) * 8);
        if (lane >= 45) hL = hz;                     // phantom s1 rows
        if (lane >= 46) hB = hz;                     // phantom s0 rows
    };

    const int h = wid;                               // my producer (0 or 1)
    int seen = 0;
    auto waitp = [&](int need) {                     // wait: my producer's pass count
        while (seen < need) {
            __builtin_amdgcn_s_sleep(1);
            seen = __hip_atomic_load(&flags[h], __ATOMIC_RELAXED,
                                     __HIP_MEMORY_SCOPE_WORKGROUP);
        }
        asm volatile("" ::: "memory");
    };

    if (wid == 0) {
        // ---- forward: alpha over t = 0..191 (chunks 0..23) ----
        float a0 = 0.f, a1 = 0.f;
        int esum = 80;
        auto step = [&](float eL, float eB) {
            const float p   = wave_shr1(a1, 0.0f);
            const float t1  = a0 + a1;
            const float na0 = (a0 + p) * eB;
            const float na1 = fmaf(skipf, p, t1) * eL;
            a0 = na0; a1 = na1;
        };
        auto renorm = [&]() {
            const float m = wave_max_bcast(fmaxf(a0, a1));
            const int e = (__float_as_int(m) >> 23) & 0xff;
            int sexp = 207 - e;                      // scale max to ~2^80
            if (sexp > 127) sexp = 127;
            const float sc = __int_as_float((sexp + 127) << 23);
            a0 *= sc; a1 *= sc;
            esum += sexp;
        };
        half8 cL, cB, nL, nB;
        waitp(1); loadch(0, cL, cB);
        for (int c = 0; c < 24; ++c) {
            if (c + 1 < 24) { waitp(c + 2); loadch(c + 1, nL, nB); }
            if (c == 0) {
                a0 = (lane == 0) ? (float)cB[0] * 0x1p80f : 0.f;
                a1 = (lane == 0) ? (float)cL[0] * 0x1p80f : 0.f;
                #pragma unroll
                for (int i = 1; i < 8; ++i) step((float)cL[i], (float)cB[i]);
            } else {
                #pragma unroll
                for (int i = 0; i < 8; ++i) step((float)cL[i], (float)cB[i]);
            }
            renorm();
            cL = nL; cB = nB;
        }
        fa0[lane] = a0;                              // raw (2^esF scaled) alpha
        fa1[lane] = a1;
        if (lane == 0) esF_s = esum;
        LDS_FENCE();
        if (lane == 0)
            __hip_atomic_store(&wdone, 1, __ATOMIC_RELAXED,
                               __HIP_MEMORY_SCOPE_WORKGROUP);
        return;
    }

    // ---- backward: beta over t = 383..192 (chunks 47..24) ----
    // G_{t-1}[s] = sum_{s'=s,s+1,s+2} allowed * e_t[s'] * G_t[s']
    float g0 = (lane == len) ? 0x1p80f : 0.f;        // state 2*len (final blank)
    float g1 = (lane == len - 1) ? 0x1p80f : 0.f;    // state 2*len-1 (last label)
    int esum = 80;
    auto bstep = [&](float eL, float eB) {
        const float h0 = g0 * eB;
        const float h1 = g1 * eL;
        const float qq = wave_shl1(fmaf(skipf, h1, h0), 0.0f);  // from lane l+1
        g0 = h0 + h1;
        g1 = h1 + qq;
    };
    auto renormB = [&]() {
        const float m = wave_max_bcast(fmaxf(g0, g1));
        const int e = (__float_as_int(m) >> 23) & 0xff;
        int sexp = 207 - e;
        if (sexp > 127) sexp = 127;
        const float sc = __int_as_float((sexp + 127) << 23);
        g0 *= sc; g1 *= sc;
        esum += sexp;
    };
    half8 cL, cB, nL, nB;
    waitp(1); loadch(47, cL, cB);
    for (int k = 0; k < 24; ++k) {
        if (k + 1 < 24) { waitp(k + 2); loadch(46 - k, nL, nB); }
        #pragma unroll
        for (int i = 7; i >= 0; --i) bstep((float)cL[i], (float)cB[i]);
        renormB();
        cL = nL; cB = nB;
    }

    // ---- join (LOG2 domain, flush-proof): P = sum_s alpha_191[s]*beta_191[s]
    int d = __hip_atomic_load(&wdone, __ATOMIC_RELAXED, __HIP_MEMORY_SCOPE_WORKGROUP);
    while (!d) {
        __builtin_amdgcn_s_sleep(1);
        d = __hip_atomic_load(&wdone, __ATOMIC_RELAXED, __HIP_MEMORY_SCOPE_WORKGROUP);
    }
    asm volatile("" ::: "memory");
    const float t0 = __log2f(fa0[lane]) + __log2f(g0);   // -inf for dead states
    const float t1 = __log2f(fa1[lane]) + __log2f(g1);
    const float m  = wave_max_bcast(fmaxf(t0, t1));      // finite: some product > 0
    const float tt = wave_sum_bcast(exp2f(t0 - m) + exp2f(t1 - m));
    if (lane == 0) {
        const float log2P = m + __log2f(tt) - (float)(esum + esF_s);
        const float nll = -0.69314718055994531f * log2P;
        atomicAdd(out, nll * inv_b);
    }
}

extern "C" void kernel_launch(void* const* d_in, const int* in_sizes, int n_in,
                              void* d_out, int out_size, void* d_ws, size_t ws_size,
                              hipStream_t stream) {
    const int* labels   = (const int*)d_in[0];
    const float* logits = (const float*)d_in[1];
    float* out          = (float*)d_out;
    (void)d_ws; (void)ws_size;

    const int L = 45, V = 60;
    const int B = in_sizes[0] / L;
    const int T = in_sizes[1] / (B * V);

    hipMemsetAsync(out, 0, (size_t)out_size * sizeof(float), stream);
    ctc_fused<<<B, 256, 0, stream>>>(labels, logits, out, T, V, L, 1.0f / (float)B);
}